// Round 1
// baseline (372.759 us; speedup 1.0000x reference)
//
#include <hip/hip_runtime.h>
#include <hip/hip_bf16.h>

#define B_ 2
#define S_ 2048
#define D_ 1024
#define H_ 16
#define HD_ 64
#define KDIM 1024

typedef __attribute__((ext_vector_type(8))) short s16x8;
typedef __attribute__((ext_vector_type(8))) __bf16 bf16x8;
typedef __attribute__((ext_vector_type(4))) float f32x4;
typedef __attribute__((ext_vector_type(4))) unsigned short u16x4;

__device__ __forceinline__ unsigned short f2bf(float f) {
  union { float f; unsigned u; } v; v.f = f;
  return (unsigned short)((v.u + 0x7FFFu + ((v.u >> 16) & 1u)) >> 16);
}

#define MFMA16(a, b, c) __builtin_amdgcn_mfma_f32_16x16x32_bf16((a), (b), (c), 0, 0, 0)

// ---------------- QKV projection: C[4096,3072] = X[4096,1024] @ W[1024,3072] + bias
// output scattered to Q/K/V [B,H,S,HD] bf16
__global__ __launch_bounds__(256) void gemm_qkv(
    const float* __restrict__ X, const float* __restrict__ W,
    const float* __restrict__ bias,
    unsigned short* __restrict__ Qo, unsigned short* __restrict__ Ko,
    unsigned short* __restrict__ Vo) {
  constexpr int NM = 3072;
  __shared__ __align__(16) unsigned short As[128][72];
  __shared__ __align__(16) unsigned short Bs[128][72];
  const int m0 = blockIdx.y * 128, n0 = blockIdx.x * 128;
  const int t = threadIdx.x;
  const int lane = t & 63, wid = t >> 6;
  const int wr = wid >> 1, wc = wid & 1;
  const int l15 = lane & 15, l16 = lane >> 4;
  f32x4 acc[4][4] = {};
  const int kk4 = (t & 15) * 4, arow0 = t >> 4;
  const int nc4 = (t & 31) * 4, brow0 = t >> 5;
  for (int k0 = 0; k0 < KDIM; k0 += 64) {
#pragma unroll
    for (int p = 0; p < 8; ++p) {
      int row = arow0 + p * 16;
      float4 v = *reinterpret_cast<const float4*>(X + (size_t)(m0 + row) * KDIM + k0 + kk4);
      u16x4 o = {f2bf(v.x), f2bf(v.y), f2bf(v.z), f2bf(v.w)};
      *reinterpret_cast<u16x4*>(&As[row][kk4]) = o;
    }
#pragma unroll
    for (int p = 0; p < 8; ++p) {
      int kr = brow0 + p * 8;
      float4 v = *reinterpret_cast<const float4*>(W + (size_t)(k0 + kr) * NM + n0 + nc4);
      Bs[nc4 + 0][kr] = f2bf(v.x);
      Bs[nc4 + 1][kr] = f2bf(v.y);
      Bs[nc4 + 2][kr] = f2bf(v.z);
      Bs[nc4 + 3][kr] = f2bf(v.w);
    }
    __syncthreads();
#pragma unroll
    for (int ks = 0; ks < 2; ++ks) {
      bf16x8 af[4], bfr[4];
#pragma unroll
      for (int m = 0; m < 4; ++m)
        af[m] = *reinterpret_cast<const bf16x8*>(&As[wr * 64 + m * 16 + l15][ks * 32 + l16 * 8]);
#pragma unroll
      for (int n = 0; n < 4; ++n)
        bfr[n] = *reinterpret_cast<const bf16x8*>(&Bs[wc * 64 + n * 16 + l15][ks * 32 + l16 * 8]);
#pragma unroll
      for (int m = 0; m < 4; ++m)
#pragma unroll
        for (int n = 0; n < 4; ++n)
          acc[m][n] = MFMA16(af[m], bfr[n], acc[m][n]);
    }
    __syncthreads();
  }
#pragma unroll
  for (int n = 0; n < 4; ++n) {
    int col = n0 + wc * 64 + n * 16 + l15;
    float bv = bias[col];
    int which = col >> 10;
    int dcol = col & 1023;
    unsigned short* dst = (which == 0) ? Qo : (which == 1) ? Ko : Vo;
    int h = dcol >> 6, hd = dcol & 63;
#pragma unroll
    for (int m = 0; m < 4; ++m) {
#pragma unroll
      for (int j = 0; j < 4; ++j) {
        int row = m0 + wr * 64 + m * 16 + l16 * 4 + j;
        int bb = row >> 11, s = row & 2047;
        size_t idx = ((((size_t)bb * H_ + h) * S_ + s) * HD_) + hd;
        dst[idx] = f2bf(acc[m][n][j] + bv);
      }
    }
  }
}

// ---------------- Flash attention, causal. One block per (b,h,q-tile of 64).
__global__ __launch_bounds__(256) void attn(
    const unsigned short* __restrict__ Qb, const unsigned short* __restrict__ Kb,
    const unsigned short* __restrict__ Vb, unsigned short* __restrict__ Cb) {
  __shared__ __align__(16) unsigned short Kl[64][72];
  __shared__ __align__(16) unsigned short Vl[64][72];  // [hd][kv]
  __shared__ __align__(16) unsigned short Pl[4][16][72];
  const int bid = blockIdx.x;
  const int qt = bid & 31;
  const int bh = bid >> 5;
  const int q0 = qt * 64;
  const int t = threadIdx.x, lane = t & 63, wid = t >> 6;
  const int l15 = lane & 15, l16 = lane >> 4;
  const size_t base = (size_t)bh * S_ * HD_;

  bf16x8 aq[2];
  {
    const unsigned short* qp = Qb + base + (size_t)(q0 + wid * 16 + l15) * HD_;
    aq[0] = *reinterpret_cast<const bf16x8*>(qp + l16 * 8);
    aq[1] = *reinterpret_cast<const bf16x8*>(qp + 32 + l16 * 8);
  }
  f32x4 o[4] = {};
  float mrow[4], lrow[4];
#pragma unroll
  for (int j = 0; j < 4; ++j) { mrow[j] = -1e30f; lrow[j] = 0.f; }

  const int scol8 = (t & 7) * 8, srow0 = t >> 3;
  const int ntile = qt + 1;
  for (int kt = 0; kt < ntile; ++kt) {
    const int kv0 = kt * 64;
#pragma unroll
    for (int p = 0; p < 2; ++p) {
      int row = srow0 + p * 32;
      s16x8 kv = *reinterpret_cast<const s16x8*>(Kb + base + (size_t)(kv0 + row) * HD_ + scol8);
      *reinterpret_cast<s16x8*>(&Kl[row][scol8]) = kv;
      s16x8 vv = *reinterpret_cast<const s16x8*>(Vb + base + (size_t)(kv0 + row) * HD_ + scol8);
#pragma unroll
      for (int j = 0; j < 8; ++j) Vl[scol8 + j][row] = (unsigned short)vv[j];
    }
    __syncthreads();
    const bool active = kv0 <= q0 + wid * 16 + 15;  // wave-uniform
    if (active) {
      f32x4 sa[4] = {};
#pragma unroll
      for (int ks = 0; ks < 2; ++ks) {
#pragma unroll
        for (int n = 0; n < 4; ++n) {
          bf16x8 bk = *reinterpret_cast<const bf16x8*>(&Kl[n * 16 + l15][ks * 32 + l16 * 8]);
          sa[n] = MFMA16(aq[ks], bk, sa[n]);
        }
      }
      float pm[4] = {-1e30f, -1e30f, -1e30f, -1e30f};
#pragma unroll
      for (int n = 0; n < 4; ++n) {
        int kvcol = kv0 + n * 16 + l15;
#pragma unroll
        for (int j = 0; j < 4; ++j) {
          int q = q0 + wid * 16 + l16 * 4 + j;
          float s = sa[n][j] * 0.125f;
          if (kvcol > q) s = -1e30f;
          sa[n][j] = s;
          pm[j] = fmaxf(pm[j], s);
        }
      }
#pragma unroll
      for (int msk = 1; msk <= 8; msk <<= 1)
#pragma unroll
        for (int j = 0; j < 4; ++j) pm[j] = fmaxf(pm[j], __shfl_xor(pm[j], msk, 64));
      float alpha[4], ps[4];
#pragma unroll
      for (int j = 0; j < 4; ++j) {
        float mn = fmaxf(mrow[j], pm[j]);
        alpha[j] = __expf(mrow[j] - mn);
        mrow[j] = mn;
        ps[j] = 0.f;
      }
#pragma unroll
      for (int n = 0; n < 4; ++n)
#pragma unroll
        for (int j = 0; j < 4; ++j) {
          float p = __expf(sa[n][j] - mrow[j]);
          sa[n][j] = p;
          ps[j] += p;
        }
#pragma unroll
      for (int msk = 1; msk <= 8; msk <<= 1)
#pragma unroll
        for (int j = 0; j < 4; ++j) ps[j] += __shfl_xor(ps[j], msk, 64);
#pragma unroll
      for (int j = 0; j < 4; ++j) lrow[j] = lrow[j] * alpha[j] + ps[j];
#pragma unroll
      for (int n = 0; n < 4; ++n)
#pragma unroll
        for (int j = 0; j < 4; ++j) o[n][j] *= alpha[j];
      // P (C-layout) -> LDS -> A-layout, wave-local
#pragma unroll
      for (int n = 0; n < 4; ++n)
#pragma unroll
        for (int j = 0; j < 4; ++j)
          Pl[wid][l16 * 4 + j][n * 16 + l15] = f2bf(sa[n][j]);
      __asm__ volatile("s_waitcnt lgkmcnt(0)" ::: "memory");
      bf16x8 pa0 = *reinterpret_cast<const bf16x8*>(&Pl[wid][l15][l16 * 8]);
      bf16x8 pa1 = *reinterpret_cast<const bf16x8*>(&Pl[wid][l15][32 + l16 * 8]);
#pragma unroll
      for (int n = 0; n < 4; ++n) {
        bf16x8 bv0 = *reinterpret_cast<const bf16x8*>(&Vl[n * 16 + l15][l16 * 8]);
        o[n] = MFMA16(pa0, bv0, o[n]);
      }
#pragma unroll
      for (int n = 0; n < 4; ++n) {
        bf16x8 bv1 = *reinterpret_cast<const bf16x8*>(&Vl[n * 16 + l15][32 + l16 * 8]);
        o[n] = MFMA16(pa1, bv1, o[n]);
      }
    }
    __syncthreads();
  }
  const int h = bh & 15, bb = bh >> 4;
#pragma unroll
  for (int n = 0; n < 4; ++n) {
#pragma unroll
    for (int j = 0; j < 4; ++j) {
      int q = q0 + wid * 16 + l16 * 4 + j;
      float val = o[n][j] / lrow[j];
      Cb[(size_t)(bb * S_ + q) * D_ + h * HD_ + n * 16 + l15] = f2bf(val);
    }
  }
}

// ---------------- Output projection: out[4096,1024] = Ctx[4096,1024] @ W[1024,1024] + bias (fp32 out)
__global__ __launch_bounds__(256) void gemm_out(
    const unsigned short* __restrict__ Xb, const float* __restrict__ W,
    const float* __restrict__ bias, float* __restrict__ out) {
  constexpr int NM = 1024;
  __shared__ __align__(16) unsigned short As[128][72];
  __shared__ __align__(16) unsigned short Bs[128][72];
  const int m0 = blockIdx.y * 128, n0 = blockIdx.x * 128;
  const int t = threadIdx.x;
  const int lane = t & 63, wid = t >> 6;
  const int wr = wid >> 1, wc = wid & 1;
  const int l15 = lane & 15, l16 = lane >> 4;
  f32x4 acc[4][4] = {};
  const int kk4 = (t & 15) * 4, arow0 = t >> 4;
  const int nc4 = (t & 31) * 4, brow0 = t >> 5;
  for (int k0 = 0; k0 < KDIM; k0 += 64) {
#pragma unroll
    for (int p = 0; p < 8; ++p) {
      int row = arow0 + p * 16;
      u16x4 v = *reinterpret_cast<const u16x4*>(Xb + (size_t)(m0 + row) * KDIM + k0 + kk4);
      *reinterpret_cast<u16x4*>(&As[row][kk4]) = v;
    }
#pragma unroll
    for (int p = 0; p < 8; ++p) {
      int kr = brow0 + p * 8;
      float4 v = *reinterpret_cast<const float4*>(W + (size_t)(k0 + kr) * NM + n0 + nc4);
      Bs[nc4 + 0][kr] = f2bf(v.x);
      Bs[nc4 + 1][kr] = f2bf(v.y);
      Bs[nc4 + 2][kr] = f2bf(v.z);
      Bs[nc4 + 3][kr] = f2bf(v.w);
    }
    __syncthreads();
#pragma unroll
    for (int ks = 0; ks < 2; ++ks) {
      bf16x8 af[4], bfr[4];
#pragma unroll
      for (int m = 0; m < 4; ++m)
        af[m] = *reinterpret_cast<const bf16x8*>(&As[wr * 64 + m * 16 + l15][ks * 32 + l16 * 8]);
#pragma unroll
      for (int n = 0; n < 4; ++n)
        bfr[n] = *reinterpret_cast<const bf16x8*>(&Bs[wc * 64 + n * 16 + l15][ks * 32 + l16 * 8]);
#pragma unroll
      for (int m = 0; m < 4; ++m)
#pragma unroll
        for (int n = 0; n < 4; ++n)
          acc[m][n] = MFMA16(af[m], bfr[n], acc[m][n]);
    }
    __syncthreads();
  }
#pragma unroll
  for (int n = 0; n < 4; ++n) {
    int col = n0 + wc * 64 + n * 16 + l15;
    float bv = bias[col];
#pragma unroll
    for (int m = 0; m < 4; ++m) {
#pragma unroll
      for (int j = 0; j < 4; ++j) {
        int row = m0 + wr * 64 + m * 16 + l16 * 4 + j;
        out[(size_t)row * NM + col] = acc[m][n][j] + bv;
      }
    }
  }
}

extern "C" void kernel_launch(void* const* d_in, const int* in_sizes, int n_in,
                              void* d_out, int out_size, void* d_ws, size_t ws_size,
                              hipStream_t stream) {
  const float* x = (const float*)d_in[0];
  const float* w_qkv = (const float*)d_in[1];
  const float* b_qkv = (const float*)d_in[2];
  const float* w_out = (const float*)d_in[3];
  const float* b_out = (const float*)d_in[4];
  float* out = (float*)d_out;

  const size_t NTOK = (size_t)B_ * H_ * S_ * HD_;  // 4,194,304 elements
  unsigned short* Qb = (unsigned short*)d_ws;
  unsigned short* Kb = Qb + NTOK;
  unsigned short* Vb = Kb + NTOK;
  unsigned short* Cb = Vb + NTOK;

  hipLaunchKernelGGL(gemm_qkv, dim3(24, 32), dim3(256), 0, stream, x, w_qkv, b_qkv, Qb, Kb, Vb);
  hipLaunchKernelGGL(attn, dim3(32 * 32), dim3(256), 0, stream, Qb, Kb, Vb, Cb);
  hipLaunchKernelGGL(gemm_out, dim3(8, 32), dim3(256), 0, stream, Cb, w_out, b_out, out);
}

// Round 2
// 175.504 us; speedup vs baseline: 2.1239x; 2.1239x over previous
//
#include <hip/hip_runtime.h>
#include <hip/hip_bf16.h>

#define B_ 2
#define S_ 2048
#define D_ 1024
#define H_ 16
#define HD_ 64
#define KDIM 1024

typedef __attribute__((ext_vector_type(8))) short s16x8;
typedef __attribute__((ext_vector_type(8))) __bf16 bf16x8;
typedef __attribute__((ext_vector_type(4))) float f32x4;
typedef __attribute__((ext_vector_type(4))) unsigned short u16x4;

__device__ __forceinline__ unsigned short f2bf(float f) {
  union { float f; unsigned u; } v; v.f = f;
  return (unsigned short)((v.u + 0x7FFFu + ((v.u >> 16) & 1u)) >> 16);
}

#define MFMA16(a, b, c) __builtin_amdgcn_mfma_f32_16x16x32_bf16((a), (b), (c), 0, 0, 0)

__device__ __forceinline__ void gll16(const void* g, void* l) {
  __builtin_amdgcn_global_load_lds(
      (const __attribute__((address_space(1))) void*)g,
      (__attribute__((address_space(3))) void*)l, 16, 0, 0);
}

// ---------------- transpose+convert: W[1024][N] fp32 -> Wt[N][1024] bf16
__global__ __launch_bounds__(256) void transpose_w(const float* __restrict__ W,
                                                   unsigned short* __restrict__ Wt,
                                                   int N) {
  __shared__ float T[64][65];
  const int k0 = blockIdx.y * 64, n0 = blockIdx.x * 64;
  const int t = threadIdx.x;
  const int lr = t >> 4, lc = (t & 15) * 4;
#pragma unroll
  for (int p = 0; p < 4; ++p) {
    const int r = lr + p * 16;
    const float4 v = *reinterpret_cast<const float4*>(W + (size_t)(k0 + r) * N + n0 + lc);
    T[r][lc + 0] = v.x; T[r][lc + 1] = v.y; T[r][lc + 2] = v.z; T[r][lc + 3] = v.w;
  }
  __syncthreads();
  const int wn = t >> 4, wk = (t & 15) * 4;
#pragma unroll
  for (int p = 0; p < 4; ++p) {
    const int n = wn + p * 16;
    u16x4 o = {f2bf(T[wk + 0][n]), f2bf(T[wk + 1][n]), f2bf(T[wk + 2][n]), f2bf(T[wk + 3][n])};
    *reinterpret_cast<u16x4*>(Wt + (size_t)(n0 + n) * 1024 + k0 + wk) = o;
  }
}

// ---------------- QKV projection: C[4096,3072] = X @ Wt^T + bias, scatter to Q/K/V [B,H,S,HD]
__global__ __launch_bounds__(256) void gemm_qkv(
    const float* __restrict__ X, const unsigned short* __restrict__ WT,
    const float* __restrict__ bias,
    unsigned short* __restrict__ Qo, unsigned short* __restrict__ Ko,
    unsigned short* __restrict__ Vo) {
  __shared__ __align__(16) unsigned short As[128][72];
  __shared__ __align__(16) unsigned short Bs[128][72];
  const int m0 = blockIdx.y * 128, n0 = blockIdx.x * 128;
  const int t = threadIdx.x;
  const int lane = t & 63, wid = t >> 6;
  const int wr = wid >> 1, wc = wid & 1;
  const int l15 = lane & 15, l16 = lane >> 4;
  f32x4 acc[4][4] = {};
  const int kk4 = (t & 15) * 4, arow0 = t >> 4;
  const int bcol8 = (t & 7) * 8, brow0 = t >> 3;
  for (int k0 = 0; k0 < KDIM; k0 += 64) {
#pragma unroll
    for (int p = 0; p < 8; ++p) {
      int row = arow0 + p * 16;
      float4 v = *reinterpret_cast<const float4*>(X + (size_t)(m0 + row) * KDIM + k0 + kk4);
      u16x4 o = {f2bf(v.x), f2bf(v.y), f2bf(v.z), f2bf(v.w)};
      *reinterpret_cast<u16x4*>(&As[row][kk4]) = o;
    }
#pragma unroll
    for (int u = 0; u < 4; ++u) {
      int row = brow0 + u * 32;
      *reinterpret_cast<s16x8*>(&Bs[row][bcol8]) =
          *reinterpret_cast<const s16x8*>(WT + (size_t)(n0 + row) * KDIM + k0 + bcol8);
    }
    __syncthreads();
#pragma unroll
    for (int ks = 0; ks < 2; ++ks) {
      bf16x8 af[4], bfr[4];
#pragma unroll
      for (int m = 0; m < 4; ++m)
        af[m] = *reinterpret_cast<const bf16x8*>(&As[wr * 64 + m * 16 + l15][ks * 32 + l16 * 8]);
#pragma unroll
      for (int n = 0; n < 4; ++n)
        bfr[n] = *reinterpret_cast<const bf16x8*>(&Bs[wc * 64 + n * 16 + l15][ks * 32 + l16 * 8]);
#pragma unroll
      for (int m = 0; m < 4; ++m)
#pragma unroll
        for (int n = 0; n < 4; ++n)
          acc[m][n] = MFMA16(af[m], bfr[n], acc[m][n]);
    }
    __syncthreads();
  }
#pragma unroll
  for (int n = 0; n < 4; ++n) {
    int col = n0 + wc * 64 + n * 16 + l15;
    float bv = bias[col];
    int which = col >> 10;
    int dcol = col & 1023;
    unsigned short* dst = (which == 0) ? Qo : (which == 1) ? Ko : Vo;
    int h = dcol >> 6, hd = dcol & 63;
#pragma unroll
    for (int m = 0; m < 4; ++m) {
#pragma unroll
      for (int j = 0; j < 4; ++j) {
        int row = m0 + wr * 64 + m * 16 + l16 * 4 + j;
        int bb = row >> 11, s = row & 2047;
        size_t idx = ((((size_t)bb * H_ + h) * S_ + s) * HD_) + hd;
        dst[idx] = f2bf(acc[m][n][j] + bv);
      }
    }
  }
}

// ---------------- Flash attention, causal, balanced pairs, dbuf, 1 barrier/iter.
__global__ __launch_bounds__(256) void attn(
    const unsigned short* __restrict__ Qb, const unsigned short* __restrict__ Kb,
    const unsigned short* __restrict__ Vb, unsigned short* __restrict__ Cb) {
  __shared__ __align__(16) unsigned short Kl[2][4096];
  __shared__ __align__(16) unsigned short Vl[2][4096];
  __shared__ __align__(16) unsigned short Pl[4][16][72];
  const int pr = blockIdx.x;   // 0..15 (pair index)
  const int bh = blockIdx.y;   // 0..31
  const int t = threadIdx.x, lane = t & 63, wid = t >> 6;
  const int l15 = lane & 15, l16 = lane >> 4;
  const size_t base = (size_t)bh * (S_ * HD_);
  const int h = bh & 15, bb = bh >> 4;
  const float NEG = -1e30f;
  const float SCALE = 0.18033688011112042f;  // (1/8) * log2(e)
  // K staging (global_load_lds): linear LDS dest, XOR-pre-swizzled global source
  const int krow8 = lane >> 3;
  const int kcolsw = ((lane & 7) ^ krow8) << 3;  // element offset within row
  // V staging: swizzled scalar transpose writes
  const int vrow = t >> 3;         // 0..31
  const int vcol8 = (t & 7) * 8;   // hd0
  const int vswz = (t & 7) << 4;   // byte swizzle key

  for (int sub = 0; sub < 2; ++sub) {
    const int qt = sub ? (31 - pr) : pr;
    const int qrow0 = qt * 64 + wid * 16;   // wave's 16 q-rows
    const int ntile = qt + 1;

    bf16x8 aq[2];
    {
      const unsigned short* qp = Qb + base + (size_t)(qrow0 + l15) * HD_;
      aq[0] = *reinterpret_cast<const bf16x8*>(qp + l16 * 8);
      aq[1] = *reinterpret_cast<const bf16x8*>(qp + 32 + l16 * 8);
    }
    f32x4 o[4] = {};
    float mrow[4], lrow[4];
#pragma unroll
    for (int j = 0; j < 4; ++j) { mrow[j] = NEG; lrow[j] = 0.f; }

    // prologue: stage tile 0 -> buffer 0
#pragma unroll
    for (int i = 0; i < 2; ++i)
      gll16(Kb + base + (size_t)(wid * 16 + i * 8 + krow8) * HD_ + kcolsw,
            &Kl[0][(wid * 16 + i * 8) * 64]);
#pragma unroll
    for (int p = 0; p < 2; ++p) {
      const int r = vrow + p * 32;
      s16x8 vv = *reinterpret_cast<const s16x8*>(Vb + base + (size_t)r * HD_ + vcol8);
#pragma unroll
      for (int j = 0; j < 8; ++j)
        *reinterpret_cast<unsigned short*>(
            reinterpret_cast<char*>(&Vl[0][0]) + (vcol8 + j) * 128 + ((r * 2) ^ vswz)) =
            (unsigned short)vv[j];
    }
    __syncthreads();

    for (int kt = 0; kt < ntile; ++kt) {
      const int cur = kt & 1, nxt = cur ^ 1;
      const int kv0 = kt * 64;
      const bool pf = (kt + 1 < ntile);
      s16x8 vpre[2];
      if (pf) {
        const int kvn = kv0 + 64;
#pragma unroll
        for (int i = 0; i < 2; ++i)
          gll16(Kb + base + (size_t)(kvn + wid * 16 + i * 8 + krow8) * HD_ + kcolsw,
                &Kl[nxt][(wid * 16 + i * 8) * 64]);
#pragma unroll
        for (int p = 0; p < 2; ++p)
          vpre[p] = *reinterpret_cast<const s16x8*>(
              Vb + base + (size_t)(kvn + vrow + p * 32) * HD_ + vcol8);
      }
      if (kv0 <= qrow0 + 15) {  // wave-uniform causal skip
        f32x4 sa[4] = {};
#pragma unroll
        for (int ks = 0; ks < 2; ++ks)
#pragma unroll
          for (int n = 0; n < 4; ++n) {
            const int row = n * 16 + l15;
            bf16x8 bk = *reinterpret_cast<const bf16x8*>(
                reinterpret_cast<const char*>(&Kl[cur][0]) + row * 128 +
                ((ks * 64 + l16 * 16) ^ ((l15 & 7) << 4)));
            sa[n] = MFMA16(aq[ks], bk, sa[n]);
          }
        float pm[4] = {NEG, NEG, NEG, NEG};
        if (kv0 + 63 > qrow0) {  // diagonal tile: mask
#pragma unroll
          for (int n = 0; n < 4; ++n) {
            const int kvcol = kv0 + n * 16 + l15;
            const int qq = qrow0 + l16 * 4;
#pragma unroll
            for (int j = 0; j < 4; ++j) {
              float s = (kvcol > qq + j) ? NEG : sa[n][j] * SCALE;
              sa[n][j] = s;
              pm[j] = fmaxf(pm[j], s);
            }
          }
        } else {
#pragma unroll
          for (int n = 0; n < 4; ++n)
#pragma unroll
            for (int j = 0; j < 4; ++j) {
              float s = sa[n][j] * SCALE;
              sa[n][j] = s;
              pm[j] = fmaxf(pm[j], s);
            }
        }
#pragma unroll
        for (int msk = 1; msk <= 8; msk <<= 1)
#pragma unroll
          for (int j = 0; j < 4; ++j)
            pm[j] = fmaxf(pm[j], __shfl_xor(pm[j], msk));
        float alpha[4], ps[4];
#pragma unroll
        for (int j = 0; j < 4; ++j) {
          const float mn = fmaxf(mrow[j], pm[j]);
          alpha[j] = exp2f(mrow[j] - mn);
          mrow[j] = mn;
          ps[j] = 0.f;
        }
#pragma unroll
        for (int n = 0; n < 4; ++n)
#pragma unroll
          for (int j = 0; j < 4; ++j) {
            const float p = exp2f(sa[n][j] - mrow[j]);
            sa[n][j] = p;
            ps[j] += p;
          }
#pragma unroll
        for (int msk = 1; msk <= 8; msk <<= 1)
#pragma unroll
          for (int j = 0; j < 4; ++j) ps[j] += __shfl_xor(ps[j], msk);
#pragma unroll
        for (int j = 0; j < 4; ++j) lrow[j] = lrow[j] * alpha[j] + ps[j];
#pragma unroll
        for (int n = 0; n < 4; ++n)
#pragma unroll
          for (int j = 0; j < 4; ++j) o[n][j] *= alpha[j];
        // P: C-layout -> LDS -> A-layout (wave-local)
#pragma unroll
        for (int n = 0; n < 4; ++n)
#pragma unroll
          for (int j = 0; j < 4; ++j)
            Pl[wid][l16 * 4 + j][n * 16 + l15] = f2bf(sa[n][j]);
        __asm__ volatile("s_waitcnt lgkmcnt(0)" ::: "memory");
        bf16x8 pa0 = *reinterpret_cast<const bf16x8*>(&Pl[wid][l15][l16 * 8]);
        bf16x8 pa1 = *reinterpret_cast<const bf16x8*>(&Pl[wid][l15][32 + l16 * 8]);
#pragma unroll
        for (int ks = 0; ks < 2; ++ks) {
          const bf16x8 pak = ks ? pa1 : pa0;
#pragma unroll
          for (int n = 0; n < 4; ++n) {
            const int hd = n * 16 + l15;
            bf16x8 bv = *reinterpret_cast<const bf16x8*>(
                reinterpret_cast<const char*>(&Vl[cur][0]) + hd * 128 +
                ((ks * 64 + l16 * 16) ^ (((hd >> 3) & 7) << 4)));
            o[n] = MFMA16(pak, bv, o[n]);
          }
        }
      }
      if (pf) {
#pragma unroll
        for (int p = 0; p < 2; ++p) {
          const int r = vrow + p * 32;
#pragma unroll
          for (int j = 0; j < 8; ++j)
            *reinterpret_cast<unsigned short*>(
                reinterpret_cast<char*>(&Vl[nxt][0]) + (vcol8 + j) * 128 + ((r * 2) ^ vswz)) =
                (unsigned short)vpre[p][j];
        }
      }
      __syncthreads();
    }
#pragma unroll
    for (int n = 0; n < 4; ++n)
#pragma unroll
      for (int j = 0; j < 4; ++j) {
        const int q = qrow0 + l16 * 4 + j;
        Cb[(size_t)(bb * S_ + q) * D_ + h * HD_ + n * 16 + l15] = f2bf(o[n][j] / lrow[j]);
      }
  }
}

// ---------------- Output projection: out[4096,1024] = Ctx @ WoT^T + bias (fp32 out)
__global__ __launch_bounds__(256) void gemm_out(
    const unsigned short* __restrict__ Xb, const unsigned short* __restrict__ WT,
    const float* __restrict__ bias, float* __restrict__ out) {
  constexpr int NM = 1024;
  __shared__ __align__(16) unsigned short As[128][72];
  __shared__ __align__(16) unsigned short Bs[128][72];
  const int m0 = blockIdx.y * 128, n0 = blockIdx.x * 128;
  const int t = threadIdx.x;
  const int lane = t & 63, wid = t >> 6;
  const int wr = wid >> 1, wc = wid & 1;
  const int l15 = lane & 15, l16 = lane >> 4;
  f32x4 acc[4][4] = {};
  const int col8 = (t & 7) * 8, row8 = t >> 3;
  for (int k0 = 0; k0 < KDIM; k0 += 64) {
#pragma unroll
    for (int u = 0; u < 4; ++u) {
      const int row = row8 + u * 32;
      *reinterpret_cast<s16x8*>(&As[row][col8]) =
          *reinterpret_cast<const s16x8*>(Xb + (size_t)(m0 + row) * KDIM + k0 + col8);
    }
#pragma unroll
    for (int u = 0; u < 4; ++u) {
      const int row = row8 + u * 32;
      *reinterpret_cast<s16x8*>(&Bs[row][col8]) =
          *reinterpret_cast<const s16x8*>(WT + (size_t)(n0 + row) * KDIM + k0 + col8);
    }
    __syncthreads();
#pragma unroll
    for (int ks = 0; ks < 2; ++ks) {
      bf16x8 af[4], bfr[4];
#pragma unroll
      for (int m = 0; m < 4; ++m)
        af[m] = *reinterpret_cast<const bf16x8*>(&As[wr * 64 + m * 16 + l15][ks * 32 + l16 * 8]);
#pragma unroll
      for (int n = 0; n < 4; ++n)
        bfr[n] = *reinterpret_cast<const bf16x8*>(&Bs[wc * 64 + n * 16 + l15][ks * 32 + l16 * 8]);
#pragma unroll
      for (int m = 0; m < 4; ++m)
#pragma unroll
        for (int n = 0; n < 4; ++n)
          acc[m][n] = MFMA16(af[m], bfr[n], acc[m][n]);
    }
    __syncthreads();
  }
#pragma unroll
  for (int n = 0; n < 4; ++n) {
    int col = n0 + wc * 64 + n * 16 + l15;
    float bv = bias[col];
#pragma unroll
    for (int m = 0; m < 4; ++m) {
#pragma unroll
      for (int j = 0; j < 4; ++j) {
        int row = m0 + wr * 64 + m * 16 + l16 * 4 + j;
        out[(size_t)row * NM + col] = acc[m][n][j] + bv;
      }
    }
  }
}

extern "C" void kernel_launch(void* const* d_in, const int* in_sizes, int n_in,
                              void* d_out, int out_size, void* d_ws, size_t ws_size,
                              hipStream_t stream) {
  const float* x = (const float*)d_in[0];
  const float* w_qkv = (const float*)d_in[1];
  const float* b_qkv = (const float*)d_in[2];
  const float* w_out = (const float*)d_in[3];
  const float* b_out = (const float*)d_in[4];
  float* out = (float*)d_out;

  const size_t NTOK = (size_t)B_ * H_ * S_ * HD_;  // 4,194,304 elements
  unsigned short* Qb = (unsigned short*)d_ws;
  unsigned short* Kb = Qb + NTOK;
  unsigned short* Vb = Kb + NTOK;
  unsigned short* Cb = Vb + NTOK;
  unsigned short* WqT = Cb + NTOK;                 // [3072][1024]
  unsigned short* WoT = WqT + (size_t)3072 * 1024; // [1024][1024]

  hipLaunchKernelGGL(transpose_w, dim3(48, 16), dim3(256), 0, stream, w_qkv, WqT, 3072);
  hipLaunchKernelGGL(transpose_w, dim3(16, 16), dim3(256), 0, stream, w_out, WoT, 1024);
  hipLaunchKernelGGL(gemm_qkv, dim3(24, 32), dim3(256), 0, stream, x, WqT, b_qkv, Qb, Kb, Vb);
  hipLaunchKernelGGL(attn, dim3(16, 32), dim3(256), 0, stream, Qb, Kb, Vb, Cb);
  hipLaunchKernelGGL(gemm_out, dim3(8, 32), dim3(256), 0, stream, Cb, WoT, b_out, out);
}

// Round 3
// 154.623 us; speedup vs baseline: 2.4108x; 1.1350x over previous
//
#include <hip/hip_runtime.h>
#include <hip/hip_bf16.h>

#define B_ 2
#define S_ 2048
#define D_ 1024
#define H_ 16
#define HD_ 64
#define KDIM 1024

typedef __attribute__((ext_vector_type(8))) short s16x8;
typedef __attribute__((ext_vector_type(8))) __bf16 bf16x8;
typedef __attribute__((ext_vector_type(4))) float f32x4;
typedef __attribute__((ext_vector_type(4))) unsigned short u16x4;

__device__ __forceinline__ unsigned short f2bf(float f) {
  union { __bf16 b; unsigned short u; } v;
  v.b = (__bf16)f;
  return v.u;
}

#define MFMA16(a, b, c) __builtin_amdgcn_mfma_f32_16x16x32_bf16((a), (b), (c), 0, 0, 0)

__device__ __forceinline__ void gll16(const void* g, void* l) {
  __builtin_amdgcn_global_load_lds(
      (const __attribute__((address_space(1))) void*)g,
      (__attribute__((address_space(3))) void*)l, 16, 0, 0);
}

// ---------------- X fp32 -> bf16
__global__ __launch_bounds__(256) void x2bf(const float* __restrict__ X,
                                            unsigned short* __restrict__ Xb) {
  const int i = (blockIdx.x * 256 + threadIdx.x) * 8;
  const float4 a = *reinterpret_cast<const float4*>(X + i);
  const float4 b = *reinterpret_cast<const float4*>(X + i + 4);
  u16x4 lo = {f2bf(a.x), f2bf(a.y), f2bf(a.z), f2bf(a.w)};
  u16x4 hi = {f2bf(b.x), f2bf(b.y), f2bf(b.z), f2bf(b.w)};
  *reinterpret_cast<u16x4*>(Xb + i) = lo;
  *reinterpret_cast<u16x4*>(Xb + i + 4) = hi;
}

// ---------------- transpose+convert: W[1024][N] fp32 -> Wt[N][1024] bf16
__global__ __launch_bounds__(256) void transpose_w(const float* __restrict__ W,
                                                   unsigned short* __restrict__ Wt,
                                                   int N) {
  __shared__ float T[64][65];
  const int k0 = blockIdx.y * 64, n0 = blockIdx.x * 64;
  const int t = threadIdx.x;
  const int lr = t >> 4, lc = (t & 15) * 4;
#pragma unroll
  for (int p = 0; p < 4; ++p) {
    const int r = lr + p * 16;
    const float4 v = *reinterpret_cast<const float4*>(W + (size_t)(k0 + r) * N + n0 + lc);
    T[r][lc + 0] = v.x; T[r][lc + 1] = v.y; T[r][lc + 2] = v.z; T[r][lc + 3] = v.w;
  }
  __syncthreads();
  const int wn = t >> 4, wk = (t & 15) * 4;
#pragma unroll
  for (int p = 0; p < 4; ++p) {
    const int n = wn + p * 16;
    u16x4 o = {f2bf(T[wk + 0][n]), f2bf(T[wk + 1][n]), f2bf(T[wk + 2][n]), f2bf(T[wk + 3][n])};
    *reinterpret_cast<u16x4*>(Wt + (size_t)(n0 + n) * 1024 + k0 + wk) = o;
  }
}

// ---------------- V[b,h,s,hd] -> Vt[b,h,hd,s]
__global__ __launch_bounds__(256) void vtrans(const unsigned short* __restrict__ Vb,
                                              unsigned short* __restrict__ Vt) {
  __shared__ unsigned short T[64][72];
  const int s0 = blockIdx.x * 64;
  const int bh = blockIdx.y;
  const int t = threadIdx.x;
  const size_t base = (size_t)bh * (S_ * HD_);
  const int r = t >> 3, c8 = (t & 7) * 8;
#pragma unroll
  for (int p = 0; p < 2; ++p)
    *reinterpret_cast<s16x8*>(&T[r + p * 32][c8]) =
        *reinterpret_cast<const s16x8*>(Vb + base + (size_t)(s0 + r + p * 32) * HD_ + c8);
  __syncthreads();
  const int hd = t & 63, sg = (t >> 6) * 8;
#pragma unroll
  for (int p = 0; p < 2; ++p) {
    unsigned short tmp[8];
#pragma unroll
    for (int j = 0; j < 8; ++j) tmp[j] = T[sg + p * 32 + j][hd];
    *reinterpret_cast<s16x8*>(Vt + base + (size_t)hd * S_ + s0 + sg + p * 32) =
        *reinterpret_cast<s16x8*>(tmp);
  }
}

// ---------------- QKV projection: [4096,3072] = Xb @ WT^T + bias -> Q/K [B,H,S,HD], V raw
__global__ __launch_bounds__(256) void gemm_qkv(
    const unsigned short* __restrict__ Xb, const unsigned short* __restrict__ WT,
    const float* __restrict__ bias,
    unsigned short* __restrict__ Qo, unsigned short* __restrict__ Ko,
    unsigned short* __restrict__ Vo) {
  __shared__ __align__(16) unsigned short As[128][72];
  __shared__ __align__(16) unsigned short Bs[128][72];
  const int m0 = blockIdx.y * 128, n0 = blockIdx.x * 128;
  const int t = threadIdx.x;
  const int lane = t & 63, wid = t >> 6;
  const int wr = wid >> 1, wc = wid & 1;
  const int l15 = lane & 15, l16 = lane >> 4;
  f32x4 acc[4][4] = {};
  const int col8 = (t & 7) * 8, row8 = t >> 3;
  for (int k0 = 0; k0 < KDIM; k0 += 64) {
#pragma unroll
    for (int u = 0; u < 4; ++u) {
      const int row = row8 + u * 32;
      *reinterpret_cast<s16x8*>(&As[row][col8]) =
          *reinterpret_cast<const s16x8*>(Xb + (size_t)(m0 + row) * KDIM + k0 + col8);
    }
#pragma unroll
    for (int u = 0; u < 4; ++u) {
      const int row = row8 + u * 32;
      *reinterpret_cast<s16x8*>(&Bs[row][col8]) =
          *reinterpret_cast<const s16x8*>(WT + (size_t)(n0 + row) * KDIM + k0 + col8);
    }
    __syncthreads();
#pragma unroll
    for (int ks = 0; ks < 2; ++ks) {
      bf16x8 af[4], bfr[4];
#pragma unroll
      for (int m = 0; m < 4; ++m)
        af[m] = *reinterpret_cast<const bf16x8*>(&As[wr * 64 + m * 16 + l15][ks * 32 + l16 * 8]);
#pragma unroll
      for (int n = 0; n < 4; ++n)
        bfr[n] = *reinterpret_cast<const bf16x8*>(&Bs[wc * 64 + n * 16 + l15][ks * 32 + l16 * 8]);
#pragma unroll
      for (int m = 0; m < 4; ++m)
#pragma unroll
        for (int n = 0; n < 4; ++n)
          acc[m][n] = MFMA16(af[m], bfr[n], acc[m][n]);
    }
    __syncthreads();
  }
#pragma unroll
  for (int n = 0; n < 4; ++n) {
    int col = n0 + wc * 64 + n * 16 + l15;
    float bv = bias[col];
    int which = col >> 10;
    int dcol = col & 1023;
    unsigned short* dst = (which == 0) ? Qo : (which == 1) ? Ko : Vo;
    int h = dcol >> 6, hd = dcol & 63;
#pragma unroll
    for (int m = 0; m < 4; ++m) {
#pragma unroll
      for (int j = 0; j < 4; ++j) {
        int row = m0 + wr * 64 + m * 16 + l16 * 4 + j;
        int bb = row >> 11, s = row & 2047;
        size_t idx = ((((size_t)bb * H_ + h) * S_ + s) * HD_) + hd;
        dst[idx] = f2bf(acc[m][n][j] + bv);
      }
    }
  }
}

// ---------------- Flash attention, causal. 1024 blocks, heavy-first, XCD-mapped.
__global__ __launch_bounds__(256) void attn(
    const unsigned short* __restrict__ Qb, const unsigned short* __restrict__ Kb,
    const unsigned short* __restrict__ Vt, unsigned short* __restrict__ Cb) {
  __shared__ __align__(16) unsigned short Kl[2][4096];
  __shared__ __align__(16) unsigned short Vl[2][4096];
  __shared__ __align__(16) unsigned short Pl[4][1024];
  const int bi = blockIdx.x;
  const int xcd = bi & 7, slot = bi >> 3;
  const int bh = xcd * 4 + (slot & 3);   // all q-tiles of a head on one XCD
  const int qt = 31 - (slot >> 2);       // heavy-first
  const int q0 = qt * 64;
  const int ntile = qt + 1;
  const int t = threadIdx.x, lane = t & 63, wid = t >> 6;
  const int l15 = lane & 15, l16 = lane >> 4;
  const size_t base = (size_t)bh * (S_ * HD_);
  const int h = bh & 15, bb = bh >> 4;
  const float NEG = -1e30f;
  const float SCALE = 0.18033688011112042f;  // (1/8)*log2(e)
  // staging: per-wave 8-row chunks, pre-swizzled global source
  const int srow = lane >> 3;
  const int scol = ((lane & 7) ^ srow) << 3;
  const int qrow0 = q0 + wid * 16;

  bf16x8 aq[2];
  {
    const unsigned short* qp = Qb + base + (size_t)(qrow0 + l15) * HD_;
    aq[0] = *reinterpret_cast<const bf16x8*>(qp + l16 * 8);
    aq[1] = *reinterpret_cast<const bf16x8*>(qp + 32 + l16 * 8);
  }
  f32x4 o[4] = {};
  float mrow[4], lrow[4];
#pragma unroll
  for (int j = 0; j < 4; ++j) { mrow[j] = NEG; lrow[j] = 0.f; }

  // prologue: stage tile 0 -> buffer 0
#pragma unroll
  for (int c = 0; c < 2; ++c) {
    const int r8 = wid * 16 + c * 8;
    gll16(Kb + base + (size_t)(r8 + srow) * HD_ + scol, &Kl[0][r8 * 64]);
    gll16(Vt + base + (size_t)(r8 + srow) * S_ + scol, &Vl[0][r8 * 64]);
  }
  __syncthreads();

  for (int kt = 0; kt < ntile; ++kt) {
    const int cur = kt & 1, nxt = cur ^ 1;
    const int kv0 = kt * 64;
    if (kt + 1 < ntile) {
      const int kvn = kv0 + 64;
#pragma unroll
      for (int c = 0; c < 2; ++c) {
        const int r8 = wid * 16 + c * 8;
        gll16(Kb + base + (size_t)(kvn + r8 + srow) * HD_ + scol, &Kl[nxt][r8 * 64]);
        gll16(Vt + base + (size_t)(r8 + srow) * S_ + kvn + scol, &Vl[nxt][r8 * 64]);
      }
    }
    // ---- QK^T
    f32x4 sa[4] = {};
#pragma unroll
    for (int ks = 0; ks < 2; ++ks)
#pragma unroll
      for (int n = 0; n < 4; ++n) {
        const int row = n * 16 + l15;
        bf16x8 bk = *reinterpret_cast<const bf16x8*>(
            reinterpret_cast<const char*>(&Kl[cur][0]) + row * 128 +
            ((ks * 64 + l16 * 16) ^ ((row & 7) << 4)));
        sa[n] = MFMA16(aq[ks], bk, sa[n]);
      }
    // ---- mask + scale + row max
    float pm[4] = {NEG, NEG, NEG, NEG};
    if (kt == qt) {
#pragma unroll
      for (int n = 0; n < 4; ++n) {
        const int kvcol = kv0 + n * 16 + l15;
        const int qq = qrow0 + l16 * 4;
#pragma unroll
        for (int j = 0; j < 4; ++j) {
          float s = (kvcol > qq + j) ? NEG : sa[n][j] * SCALE;
          sa[n][j] = s;
          pm[j] = fmaxf(pm[j], s);
        }
      }
    } else {
#pragma unroll
      for (int n = 0; n < 4; ++n)
#pragma unroll
        for (int j = 0; j < 4; ++j) {
          float s = sa[n][j] * SCALE;
          sa[n][j] = s;
          pm[j] = fmaxf(pm[j], s);
        }
    }
#pragma unroll
    for (int msk = 1; msk <= 8; msk <<= 1)
#pragma unroll
      for (int j = 0; j < 4; ++j)
        pm[j] = fmaxf(pm[j], __shfl_xor(pm[j], msk));
    // ---- exact skip-rescale: only rescale if some row got a new max
    bool anew = false;
#pragma unroll
    for (int j = 0; j < 4; ++j) anew = anew || (pm[j] > mrow[j]);
    if (__any(anew)) {
      float alpha[4];
#pragma unroll
      for (int j = 0; j < 4; ++j) {
        const float mn = fmaxf(mrow[j], pm[j]);
        alpha[j] = exp2f(mrow[j] - mn);
        mrow[j] = mn;
        lrow[j] *= alpha[j];
      }
#pragma unroll
      for (int n = 0; n < 4; ++n)
#pragma unroll
        for (int j = 0; j < 4; ++j) o[n][j] *= alpha[j];
    }
    float ps[4] = {0.f, 0.f, 0.f, 0.f};
#pragma unroll
    for (int n = 0; n < 4; ++n)
#pragma unroll
      for (int j = 0; j < 4; ++j) {
        const float p = exp2f(sa[n][j] - mrow[j]);
        sa[n][j] = p;
        ps[j] += p;
      }
#pragma unroll
    for (int msk = 1; msk <= 8; msk <<= 1)
#pragma unroll
      for (int j = 0; j < 4; ++j) ps[j] += __shfl_xor(ps[j], msk);
#pragma unroll
    for (int j = 0; j < 4; ++j) lrow[j] += ps[j];
    // ---- P: C-layout -> LDS (XOR-swizzled) -> A-layout, wave-local
#pragma unroll
    for (int n = 0; n < 4; ++n)
#pragma unroll
      for (int j = 0; j < 4; ++j) {
        const int row = l16 * 4 + j;
        const int cb = (n * 32 + l15 * 2) ^ ((row & 7) << 4);
        *reinterpret_cast<unsigned short*>(
            reinterpret_cast<char*>(&Pl[wid][0]) + row * 128 + cb) = f2bf(sa[n][j]);
      }
    __asm__ volatile("s_waitcnt lgkmcnt(0)" ::: "memory");
    const char* pb = reinterpret_cast<const char*>(&Pl[wid][0]) + l15 * 128;
    const int pkey = (l15 & 7) << 4;
    bf16x8 pa0 = *reinterpret_cast<const bf16x8*>(pb + ((l16 * 16) ^ pkey));
    bf16x8 pa1 = *reinterpret_cast<const bf16x8*>(pb + ((64 + l16 * 16) ^ pkey));
    // ---- PV from Vt (same swizzled pattern as K)
#pragma unroll
    for (int ks = 0; ks < 2; ++ks) {
      const bf16x8 pak = ks ? pa1 : pa0;
#pragma unroll
      for (int n = 0; n < 4; ++n) {
        const int row = n * 16 + l15;
        bf16x8 bv = *reinterpret_cast<const bf16x8*>(
            reinterpret_cast<const char*>(&Vl[cur][0]) + row * 128 +
            ((ks * 64 + l16 * 16) ^ ((row & 7) << 4)));
        o[n] = MFMA16(pak, bv, o[n]);
      }
    }
    __syncthreads();
  }
#pragma unroll
  for (int n = 0; n < 4; ++n)
#pragma unroll
    for (int j = 0; j < 4; ++j) {
      const int q = qrow0 + l16 * 4 + j;
      Cb[(size_t)(bb * S_ + q) * D_ + h * HD_ + n * 16 + l15] = f2bf(o[n][j] / lrow[j]);
    }
}

// ---------------- Output projection: out[4096,1024] = Ctx @ WoT^T + bias (fp32 out)
__global__ __launch_bounds__(256) void gemm_out(
    const unsigned short* __restrict__ Xb, const unsigned short* __restrict__ WT,
    const float* __restrict__ bias, float* __restrict__ out) {
  constexpr int NM = 1024;
  __shared__ __align__(16) unsigned short As[128][72];
  __shared__ __align__(16) unsigned short Bs[128][72];
  const int m0 = blockIdx.y * 128, n0 = blockIdx.x * 128;
  const int t = threadIdx.x;
  const int lane = t & 63, wid = t >> 6;
  const int wr = wid >> 1, wc = wid & 1;
  const int l15 = lane & 15, l16 = lane >> 4;
  f32x4 acc[4][4] = {};
  const int col8 = (t & 7) * 8, row8 = t >> 3;
  for (int k0 = 0; k0 < KDIM; k0 += 64) {
#pragma unroll
    for (int u = 0; u < 4; ++u) {
      const int row = row8 + u * 32;
      *reinterpret_cast<s16x8*>(&As[row][col8]) =
          *reinterpret_cast<const s16x8*>(Xb + (size_t)(m0 + row) * KDIM + k0 + col8);
    }
#pragma unroll
    for (int u = 0; u < 4; ++u) {
      const int row = row8 + u * 32;
      *reinterpret_cast<s16x8*>(&Bs[row][col8]) =
          *reinterpret_cast<const s16x8*>(WT + (size_t)(n0 + row) * KDIM + k0 + col8);
    }
    __syncthreads();
#pragma unroll
    for (int ks = 0; ks < 2; ++ks) {
      bf16x8 af[4], bfr[4];
#pragma unroll
      for (int m = 0; m < 4; ++m)
        af[m] = *reinterpret_cast<const bf16x8*>(&As[wr * 64 + m * 16 + l15][ks * 32 + l16 * 8]);
#pragma unroll
      for (int n = 0; n < 4; ++n)
        bfr[n] = *reinterpret_cast<const bf16x8*>(&Bs[wc * 64 + n * 16 + l15][ks * 32 + l16 * 8]);
#pragma unroll
      for (int m = 0; m < 4; ++m)
#pragma unroll
        for (int n = 0; n < 4; ++n)
          acc[m][n] = MFMA16(af[m], bfr[n], acc[m][n]);
    }
    __syncthreads();
  }
#pragma unroll
  for (int n = 0; n < 4; ++n) {
    int col = n0 + wc * 64 + n * 16 + l15;
    float bv = bias[col];
#pragma unroll
    for (int m = 0; m < 4; ++m) {
#pragma unroll
      for (int j = 0; j < 4; ++j) {
        int row = m0 + wr * 64 + m * 16 + l16 * 4 + j;
        out[(size_t)row * NM + col] = acc[m][n][j] + bv;
      }
    }
  }
}

extern "C" void kernel_launch(void* const* d_in, const int* in_sizes, int n_in,
                              void* d_out, int out_size, void* d_ws, size_t ws_size,
                              hipStream_t stream) {
  const float* x = (const float*)d_in[0];
  const float* w_qkv = (const float*)d_in[1];
  const float* b_qkv = (const float*)d_in[2];
  const float* w_out = (const float*)d_in[3];
  const float* b_out = (const float*)d_in[4];
  float* out = (float*)d_out;

  const size_t NTOK = (size_t)B_ * H_ * S_ * HD_;  // 4,194,304 elements
  unsigned short* Qb = (unsigned short*)d_ws;
  unsigned short* Kb = Qb + NTOK;
  unsigned short* Vt = Kb + NTOK;                  // transposed V [b,h,hd,s]
  unsigned short* Vb = Vt + NTOK;                  // raw V (temp)
  unsigned short* WqT = Vb + NTOK;                 // [3072][1024]
  unsigned short* WoT = WqT + (size_t)3072 * 1024; // [1024][1024]
  unsigned short* Xbf = WoT + (size_t)1024 * 1024; // [4096][1024]
  unsigned short* Cb = Xbf;                        // alias: Xbf dead before attn writes Cb

  hipLaunchKernelGGL(x2bf, dim3(2048), dim3(256), 0, stream, x, Xbf);
  hipLaunchKernelGGL(transpose_w, dim3(48, 16), dim3(256), 0, stream, w_qkv, WqT, 3072);
  hipLaunchKernelGGL(transpose_w, dim3(16, 16), dim3(256), 0, stream, w_out, WoT, 1024);
  hipLaunchKernelGGL(gemm_qkv, dim3(24, 32), dim3(256), 0, stream, Xbf, WqT, b_qkv, Qb, Kb, Vb);
  hipLaunchKernelGGL(vtrans, dim3(32, 32), dim3(256), 0, stream, Vb, Vt);
  hipLaunchKernelGGL(attn, dim3(1024), dim3(256), 0, stream, Qb, Kb, Vt, Cb);
  hipLaunchKernelGGL(gemm_out, dim3(8, 32), dim3(256), 0, stream, Cb, WoT, b_out, out);
}